// Round 12
// baseline (867.167 us; speedup 1.0000x reference)
//
#include <hip/hip_runtime.h>
#include <hip/hip_bf16.h>

typedef unsigned short u16;
typedef __attribute__((ext_vector_type(8))) short bf16x8;
typedef __attribute__((ext_vector_type(4))) float f32x4;

#define DEVINL __device__ __forceinline__

DEVINL u16 f2b(float f) {
    __hip_bfloat16 h = __float2bfloat16(f);
    return __builtin_bit_cast(u16, h);
}
DEVINL float b2f(u16 u) {
    unsigned int x = ((unsigned int)u) << 16;
    return __builtin_bit_cast(float, x);
}
DEVINL int iabs(int x) { return x < 0 ? -x : x; }
DEVINL f32x4 MFMA(bf16x8 a, bf16x8 b, f32x4 c) {
    return __builtin_amdgcn_mfma_f32_16x16x32_bf16(a, b, c, 0, 0, 0);
}

#define GL2LDS(g, s)                                                                     \
    __builtin_amdgcn_global_load_lds(                                                    \
        (const __attribute__((address_space(1))) unsigned int*)(g),                      \
        (__attribute__((address_space(3))) unsigned int*)(s), 16, 0, 0)

// ---------------------------------------------------------------------------
// Weight convert + transpose.
// z<3 (wq,wk,wv): w[k][n] f32, n = head*64+d  ->  wqkvt[head*192 + z*64 + d][k] bf16
// z==3 (wo): wot[n][k] bf16 (plain B^T)
// ---------------------------------------------------------------------------
__global__ __launch_bounds__(256) void wconv_kernel(const float* __restrict__ wq,
                                                    const float* __restrict__ wk,
                                                    const float* __restrict__ wv,
                                                    const float* __restrict__ wo,
                                                    u16* __restrict__ wqkvt,
                                                    u16* __restrict__ wot) {
    __shared__ float tile[32][33];
    int z = blockIdx.z;
    const float* src = (z == 0) ? wq : (z == 1) ? wk : (z == 2) ? wv : wo;
    int n0 = blockIdx.x * 32, k0 = blockIdx.y * 32;
    int r0 = threadIdx.x >> 5, c = threadIdx.x & 31;
#pragma unroll
    for (int i = 0; i < 4; i++) {
        int r = r0 + i * 8;
        tile[r][c] = src[(size_t)(k0 + r) * 1024 + n0 + c];
    }
    __syncthreads();
    u16* dst = (z < 3) ? wqkvt : wot;
#pragma unroll
    for (int i = 0; i < 4; i++) {
        int r = r0 + i * 8;
        int nn = n0 + r;
        size_t drow = (z < 3) ? ((size_t)(nn >> 6) * 192 + (size_t)z * 64 + (nn & 63))
                              : (size_t)nn;
        dst[drow * 1024 + k0 + c] = f2b(tile[c][r]);
    }
}

// ---------------------------------------------------------------------------
// LayerNorm: one wave per 1024-elem row, output bf16
// ---------------------------------------------------------------------------
__global__ __launch_bounds__(256) void ln_kernel(const float* __restrict__ x,
                                                 const float* __restrict__ gamma,
                                                 const float* __restrict__ beta,
                                                 u16* __restrict__ h) {
    int w = threadIdx.x >> 6, l = threadIdx.x & 63;
    size_t row = (size_t)blockIdx.x * 4 + w;
    const float4* xr = (const float4*)(x + row * 1024);
    float4 v[4];
    float s = 0.f, sq = 0.f;
#pragma unroll
    for (int i = 0; i < 4; i++) {
        v[i] = xr[l + i * 64];
        s += v[i].x + v[i].y + v[i].z + v[i].w;
        sq += v[i].x * v[i].x + v[i].y * v[i].y + v[i].z * v[i].z + v[i].w * v[i].w;
    }
#pragma unroll
    for (int off = 1; off < 64; off <<= 1) {
        s += __shfl_xor(s, off);
        sq += __shfl_xor(sq, off);
    }
    float mu = s * (1.f / 1024.f);
    float var = sq * (1.f / 1024.f) - mu * mu;
    float rstd = rsqrtf(var + 1e-5f);
    const float4* g4 = (const float4*)gamma;
    const float4* b4 = (const float4*)beta;
#pragma unroll
    for (int i = 0; i < 4; i++) {
        float4 g = g4[l + i * 64], b = b4[l + i * 64];
        float y0 = (v[i].x - mu) * rstd * g.x + b.x;
        float y1 = (v[i].y - mu) * rstd * g.y + b.y;
        float y2 = (v[i].z - mu) * rstd * g.z + b.z;
        float y3 = (v[i].w - mu) * rstd * g.w + b.w;
        unsigned int lo = (unsigned int)f2b(y0) | ((unsigned int)f2b(y1) << 16);
        unsigned int hi = (unsigned int)f2b(y2) | ((unsigned int)f2b(y3) << 16);
        uint2 pk;
        pk.x = lo;
        pk.y = hi;
        *(uint2*)(h + row * 1024 + (size_t)(l + i * 64) * 4) = pk;
    }
}

// ---------------------------------------------------------------------------
// Fused QKV-projection + attention (R12: fat-wave variant of the R8 winner).
// One block = 112 rows (4 seqs) x 192 cols (one head's q|k|v). 128 threads,
// 2 waves, each 112x96 (7x6 frags, 168 acc VGPRs). Rationale: R8's 1Mx4N grid
// read A 4x from LDS -> 488 B/MFMA > ~85 B/cy LDS ceiling (util capped 42%).
// 112x96 waves: 317 B/MFMA -> MFMA-bound. LDS unchanged 38912 B -> 4 blocks/CU.
// Same 2-barrier K-loop, same swizzles, same decomposition (bm fast, head
// alternating per XCD).
//   GEMM: sA [0,14336) = 112 rows x 128B; sB [14336,38912) = 192 rows x 128B.
// Attn epilogue (2-wave mapping, layouts identical to R8):
//   P1: q,k -> qkb swizzled [112][128] u16 @0 (wave0: cols 0-95; wave1: 96-127).
//   P2: 8 tasks (seq,ihalf) over 2 waves (4 each): 4 QK^T MFMAs + softmax of
//       16 rows -> sp slot [16][40] @28672 + slot*1280.
//   P3: wave1 scatters v -> vt u16[4][64][40] @0 over dead qkb.
//   P4: 4 PV tasks/wave: 4 MFMAs + ctx write (dense [57344][1024]).
// Garbage audit (= R8): P2 b1-rows 112..115 land in sp region -> only j>=28
// scores, masked to -1e30 before exp; score rows i>=28 discarded.
// ---------------------------------------------------------------------------
__global__ __launch_bounds__(128) void fused_qkv_attn(const u16* __restrict__ h,
                                                      const u16* __restrict__ wqkvt,
                                                      u16* __restrict__ ctx) {
    __shared__ __align__(16) char smem[38912];
    char* sA = smem;
    char* sB = smem + 14336;
    int t = threadIdx.x;

    int nwg = gridDim.x;  // 8192
    int cpx = nwg >> 3;
    int wg = ((int)blockIdx.x & 7) * cpx + ((int)blockIdx.x >> 3);
    int x = wg >> 10;                // XCD 0..7
    int i0 = wg & 1023;
    int bm = i0 >> 1;                // 0..511 (fast)
    int head = (x << 1) | (i0 & 1);  // 0..15

    // staging: 128 threads cover 16 rows (2048B) per chunk; XOR swizzle on source
    int p16 = t * 16;
    int srow = p16 >> 7;  // 0..15
    int scolb = (p16 & 127) ^ ((srow & 7) << 4);
    const char* aB = (const char*)h + ((size_t)bm * 112 + srow) * 2048 + scolb;
    const char* bB = (const char*)wqkvt + ((size_t)head * 192 + srow) * 2048 + scolb;

    int l = t & 63, w = t >> 6, g = l >> 4, lr = l & 15;
    int swz = (lr & 7) << 4;

    f32x4 acc[7][6];
#pragma unroll
    for (int m = 0; m < 7; m++)
#pragma unroll
        for (int n = 0; n < 6; n++) acc[m][n] = {0.f, 0.f, 0.f, 0.f};

#pragma unroll 1
    for (int kt = 0; kt < 16; ++kt) {
        int kb = kt * 128;
#pragma unroll
        for (int i = 0; i < 7; i++) GL2LDS(aB + (size_t)i * 32768 + kb, sA + i * 2048 + p16);
#pragma unroll
        for (int i = 0; i < 12; i++) GL2LDS(bB + (size_t)i * 32768 + kb, sB + i * 2048 + p16);
        __syncthreads();
#pragma unroll
        for (int ks = 0; ks < 2; ++ks) {
            bf16x8 af[7], bfv[6];
#pragma unroll
            for (int m = 0; m < 7; m++)
                af[m] = *(const bf16x8*)(sA + (m * 16 + lr) * 128 + ((ks * 64 + g * 16) ^ swz));
#pragma unroll
            for (int n = 0; n < 6; n++)
                bfv[n] = *(const bf16x8*)(sB + (w * 96 + n * 16 + lr) * 128 +
                                          ((ks * 64 + g * 16) ^ swz));
#pragma unroll
            for (int m = 0; m < 7; m++)
#pragma unroll
                for (int n = 0; n < 6; n++) acc[m][n] = MFMA(af[m], bfv[n], acc[m][n]);
        }
        __syncthreads();
    }

    // ---------------- epilogue phase 1: q,k -> swizzled qkb ----------------
    u16* qkb = (u16*)smem;                     // [112][128] swizzled
    u16(*vt)[64][40] = (u16(*)[64][40])smem;   // phase-3 alias (20480B)
    char* spbase = smem + 28672;               // 8 slots x [16][40] (10240B)

#pragma unroll
    for (int m = 0; m < 7; m++)
#pragma unroll
        for (int n = 0; n < 6; n++) {
            int col = w * 96 + n * 16 + lr;
            if (col < 128) {
#pragma unroll
                for (int r = 0; r < 4; ++r) {
                    int row = m * 16 + g * 4 + r;
                    qkb[row * 128 + (col ^ ((row & 7) << 3))] = f2b(acc[m][n][r]);
                }
            }
        }
    __syncthreads();

    // ---------------- phase 2: QK^T + softmax (4 tasks per wave) ----------------
    float slope = exp2f(-0.5f * (float)(head + 1));
    int j0 = lr, j1 = 16 + lr;
    int j0m = j0 % 14, j0d = j0 / 14;
    int j1m = j1 % 14, j1d = j1 / 14;

#pragma unroll
    for (int q = 0; q < 4; ++q) {
        int seq = w * 2 + (q >> 1), ih = q & 1;
        int rb = seq * 28;
        u16(*spw)[40] = (u16(*)[40])(spbase + (w * 4 + q) * 1280);
        f32x4 sc0 = {0.f, 0.f, 0.f, 0.f}, sc1 = {0.f, 0.f, 0.f, 0.f};
#pragma unroll
        for (int c = 0; c < 2; ++c) {
            int u0 = c * 32 + g * 8;
            int arow = rb + ih * 16 + lr;
            int br0 = rb + lr, br1 = rb + 16 + lr;
            bf16x8 aa = *(const bf16x8*)&qkb[arow * 128 + (u0 ^ ((arow & 7) << 3))];
            bf16x8 b0 = *(const bf16x8*)&qkb[br0 * 128 + ((64 + u0) ^ ((br0 & 7) << 3))];
            bf16x8 b1 = *(const bf16x8*)&qkb[br1 * 128 + ((64 + u0) ^ ((br1 & 7) << 3))];
            sc0 = MFMA(aa, b0, sc0);
            sc1 = MFMA(aa, b1, sc1);
        }
#pragma unroll
        for (int r = 0; r < 4; ++r) {
            int i = ih * 16 + g * 4 + r;
            int im = i % 14, id = i / 14;
            float s0 = sc0[r] + slope * (float)(iabs(im - j0m) + iabs(id - j0d));
            float s1 = (j1 < 28)
                           ? sc1[r] + slope * (float)(iabs(im - j1m) + iabs(id - j1d))
                           : -1e30f;
            float mx = fmaxf(s0, s1);
#pragma unroll
            for (int off = 1; off < 16; off <<= 1) mx = fmaxf(mx, __shfl_xor(mx, off));
            float e0 = __expf(s0 - mx), e1 = __expf(s1 - mx);
            float sm = e0 + e1;
#pragma unroll
            for (int off = 1; off < 16; off <<= 1) sm += __shfl_xor(sm, off);
            float inv = 1.f / sm;
            spw[g * 4 + r][lr] = f2b(e0 * inv);
            spw[g * 4 + r][16 + lr] = f2b(e1 * inv);
        }
    }
    __syncthreads();  // all QK^T reads of qkb done -> region reusable for vt

    // ---------------- phase 3: v -> vt over dead qkb ----------------
#pragma unroll
    for (int it = 0; it < 2; ++it) {
        int idx = t + it * 128;
        int s2 = idx >> 6, d = idx & 63;
#pragma unroll
        for (int j = 28; j < 32; ++j) vt[s2][d][j] = 0;
    }
    if (w == 1) {
#pragma unroll
        for (int m = 0; m < 7; m++)
#pragma unroll
            for (int n = 2; n < 6; n++) {
                int col = 96 + n * 16 + lr;  // 128..191
                int d = col - 128;
#pragma unroll
                for (int r = 0; r < 4; ++r) {
                    int row = m * 16 + g * 4 + r;
                    int s2 = row / 28;
                    int j = row - s2 * 28;
                    vt[s2][d][j] = f2b(acc[m][n][r]);
                }
            }
    }
    __syncthreads();

    // ---------------- phase 4: PV (4 tasks per wave) + ctx write ----------------
#pragma unroll
    for (int q = 0; q < 4; ++q) {
        int seq = w * 2 + (q >> 1), ih = q & 1;
        u16(*spw)[40] = (u16(*)[40])(spbase + (w * 4 + q) * 1280);
        bf16x8 pa = *(const bf16x8*)&spw[lr][g * 8];
        f32x4 o[4];
#pragma unroll
        for (int d = 0; d < 4; d++) o[d] = {0.f, 0.f, 0.f, 0.f};
#pragma unroll
        for (int dt = 0; dt < 4; ++dt) {
            bf16x8 bv = *(const bf16x8*)&vt[seq][dt * 16 + lr][g * 8];
            o[dt] = MFMA(pa, bv, o[dt]);
        }
#pragma unroll
        for (int dt = 0; dt < 4; ++dt)
#pragma unroll
            for (int r = 0; r < 4; ++r) {
                int i = ih * 16 + g * 4 + r;
                if (i < 28) {
                    size_t off =
                        ((size_t)(bm * 4 + seq) * 28 + i) * 1024 + head * 64 + dt * 16 + lr;
                    ctx[off] = f2b(o[dt][r]);
                }
            }
    }
}

// ---------------------------------------------------------------------------
// GEMM (round-1 verbatim): C[M,N] = A[M,1024] bf16 x Bt[N,1024] bf16.
// 128x128 tile, BK=64x2, 256 threads. Used for the output projection.
// ---------------------------------------------------------------------------
template <int OUT_BF16, int RESID>
__global__ __launch_bounds__(256, 2) void gemm_bt(const u16* __restrict__ A,
                                                  const u16* __restrict__ Bt,
                                                  void* __restrict__ Cv,
                                                  const u16* __restrict__ resid,
                                                  int lda, int ldc) {
    __shared__ u16 smem[16384];
    int t = threadIdx.x;

    int nwg = gridDim.x;
    int cpx = nwg >> 3;
    int wg = (blockIdx.x & 7) * cpx + (blockIdx.x >> 3);
    const int sgrp = 448 * 8;
    int sn = wg / sgrp;
    int rem = wg - sn * sgrp;
    int bm = rem >> 3;
    int bn = sn * 8 + (rem & 7);

    const char* Ab = (const char*)A;
    const char* Bb = (const char*)Bt;
    size_t aoffg[4], boffg[4];
#pragma unroll
    for (int i = 0; i < 4; i++) {
        int p = t * 16 + i * 4096;
        int row = p >> 7;
        int colb = (p & 127) ^ ((row & 7) << 4);
        aoffg[i] = (size_t)(bm * 128 + row) * (size_t)lda * 2 + colb;
        boffg[i] = (size_t)(bn * 128 + row) * 2048 + colb;
    }
    char* sA = (char*)smem;
    char* sB = sA + 16384;

    int l = t & 63, w = t >> 6;
    int wm = w >> 1, wn = w & 1, g = l >> 4, lr = l & 15;
    int swz = (lr & 7) << 4;

    f32x4 acc[4][4];
#pragma unroll
    for (int m = 0; m < 4; m++)
#pragma unroll
        for (int n = 0; n < 4; n++) acc[m][n] = {0.f, 0.f, 0.f, 0.f};

    for (int kt = 0; kt < 16; ++kt) {
        int kb = kt * 128;
#pragma unroll
        for (int i = 0; i < 4; i++) GL2LDS(Ab + aoffg[i] + kb, sA + i * 4096 + t * 16);
#pragma unroll
        for (int i = 0; i < 4; i++) GL2LDS(Bb + boffg[i] + kb, sB + i * 4096 + t * 16);
        __syncthreads();
#pragma unroll
        for (int ks = 0; ks < 2; ++ks) {
            bf16x8 af[4], bfv[4];
#pragma unroll
            for (int m = 0; m < 4; m++)
                af[m] = *(const bf16x8*)(sA + (wm * 64 + m * 16 + lr) * 128 +
                                         ((ks * 64 + g * 16) ^ swz));
#pragma unroll
            for (int n = 0; n < 4; n++)
                bfv[n] = *(const bf16x8*)(sB + (wn * 64 + n * 16 + lr) * 128 +
                                          ((ks * 64 + g * 16) ^ swz));
#pragma unroll
            for (int m = 0; m < 4; m++)
#pragma unroll
                for (int n = 0; n < 4; n++)
                    acc[m][n] = MFMA(af[m], bfv[n], acc[m][n]);
        }
        __syncthreads();
    }

    size_t row0 = (size_t)bm * 128 + wm * 64;
    int col0 = bn * 128 + wn * 64;
    if (OUT_BF16) {
        u16* C = (u16*)Cv;
#pragma unroll
        for (int m = 0; m < 4; m++)
#pragma unroll
            for (int n = 0; n < 4; n++)
#pragma unroll
                for (int r = 0; r < 4; r++) {
                    size_t rr = row0 + m * 16 + g * 4 + r;
                    int cc = col0 + n * 16 + lr;
                    C[rr * (size_t)ldc + cc] = f2b(acc[m][n][r]);
                }
    } else {
        float* C = (float*)Cv;
#pragma unroll
        for (int m = 0; m < 4; m++)
#pragma unroll
            for (int n = 0; n < 4; n++)
#pragma unroll
                for (int r = 0; r < 4; r++) {
                    size_t rr = row0 + m * 16 + g * 4 + r;
                    int cc = col0 + n * 16 + lr;
                    float o = acc[m][n][r];
                    if (RESID) o += b2f(resid[rr * 1024 + cc]);
                    C[rr * (size_t)ldc + cc] = o;
                }
    }
}

// ---------------------------------------------------------------------------
extern "C" void kernel_launch(void* const* d_in, const int* in_sizes, int n_in,
                              void* d_out, int out_size, void* d_ws, size_t ws_size,
                              hipStream_t stream) {
    (void)in_sizes; (void)n_in; (void)out_size; (void)ws_size;
    const float* hidden = (const float*)d_in[0];
    const float* wq = (const float*)d_in[1];
    const float* wk = (const float*)d_in[2];
    const float* wv = (const float*)d_in[3];
    const float* wo = (const float*)d_in[4];
    const float* gamma = (const float*)d_in[5];
    const float* beta = (const float*)d_in[6];
    float* out = (float*)d_out;

    char* ws = (char*)d_ws;
    u16* h = (u16*)ws;                                  // 117,440,512 B
    u16* ctx = (u16*)(ws + 117440512);                  // 117,440,512 B
    u16* wqkvt = (u16*)(ws + 234881024);                //   6,291,456 B
    u16* wot = (u16*)(ws + 234881024 + 6291456);        //   2,097,152 B

    wconv_kernel<<<dim3(32, 32, 4), 256, 0, stream>>>(wq, wk, wv, wo, wqkvt, wot);
    ln_kernel<<<14336, 256, 0, stream>>>(hidden, gamma, beta, h);
    fused_qkv_attn<<<8192, 128, 0, stream>>>(h, wqkvt, ctx);
    // ctx is dense [57344][1024] -> lda = 1024
    gemm_bt<0, 1><<<448 * 8, 256, 0, stream>>>(ctx, wot, out, h, 1024, 1024);
}

// Round 13
// 624.943 us; speedup vs baseline: 1.3876x; 1.3876x over previous
//
#include <hip/hip_runtime.h>
#include <hip/hip_bf16.h>

typedef unsigned short u16;
typedef __attribute__((ext_vector_type(8))) short bf16x8;
typedef __attribute__((ext_vector_type(4))) float f32x4;

#define DEVINL __device__ __forceinline__

DEVINL u16 f2b(float f) {
    __hip_bfloat16 h = __float2bfloat16(f);
    return __builtin_bit_cast(u16, h);
}
DEVINL float b2f(u16 u) {
    unsigned int x = ((unsigned int)u) << 16;
    return __builtin_bit_cast(float, x);
}
DEVINL int iabs(int x) { return x < 0 ? -x : x; }
DEVINL f32x4 MFMA(bf16x8 a, bf16x8 b, f32x4 c) {
    return __builtin_amdgcn_mfma_f32_16x16x32_bf16(a, b, c, 0, 0, 0);
}

#define GL2LDS(g, s)                                                                     \
    __builtin_amdgcn_global_load_lds(                                                    \
        (const __attribute__((address_space(1))) unsigned int*)(g),                      \
        (__attribute__((address_space(3))) unsigned int*)(s), 16, 0, 0)

// ---------------------------------------------------------------------------
// Weight convert + transpose.
// z<3 (wq,wk,wv): w[k][n] f32, n = head*64+d  ->  wqkvt[head*192 + z*64 + d][k] bf16
// z==3 (wo): wot[n][k] bf16 (plain B^T)
// ---------------------------------------------------------------------------
__global__ __launch_bounds__(256) void wconv_kernel(const float* __restrict__ wq,
                                                    const float* __restrict__ wk,
                                                    const float* __restrict__ wv,
                                                    const float* __restrict__ wo,
                                                    u16* __restrict__ wqkvt,
                                                    u16* __restrict__ wot) {
    __shared__ float tile[32][33];
    int z = blockIdx.z;
    const float* src = (z == 0) ? wq : (z == 1) ? wk : (z == 2) ? wv : wo;
    int n0 = blockIdx.x * 32, k0 = blockIdx.y * 32;
    int r0 = threadIdx.x >> 5, c = threadIdx.x & 31;
#pragma unroll
    for (int i = 0; i < 4; i++) {
        int r = r0 + i * 8;
        tile[r][c] = src[(size_t)(k0 + r) * 1024 + n0 + c];
    }
    __syncthreads();
    u16* dst = (z < 3) ? wqkvt : wot;
#pragma unroll
    for (int i = 0; i < 4; i++) {
        int r = r0 + i * 8;
        int nn = n0 + r;
        size_t drow = (z < 3) ? ((size_t)(nn >> 6) * 192 + (size_t)z * 64 + (nn & 63))
                              : (size_t)nn;
        dst[drow * 1024 + k0 + c] = f2b(tile[c][r]);
    }
}

// ---------------------------------------------------------------------------
// LayerNorm: one wave per 1024-elem row, output bf16
// ---------------------------------------------------------------------------
__global__ __launch_bounds__(256) void ln_kernel(const float* __restrict__ x,
                                                 const float* __restrict__ gamma,
                                                 const float* __restrict__ beta,
                                                 u16* __restrict__ h) {
    int w = threadIdx.x >> 6, l = threadIdx.x & 63;
    size_t row = (size_t)blockIdx.x * 4 + w;
    const float4* xr = (const float4*)(x + row * 1024);
    float4 v[4];
    float s = 0.f, sq = 0.f;
#pragma unroll
    for (int i = 0; i < 4; i++) {
        v[i] = xr[l + i * 64];
        s += v[i].x + v[i].y + v[i].z + v[i].w;
        sq += v[i].x * v[i].x + v[i].y * v[i].y + v[i].z * v[i].z + v[i].w * v[i].w;
    }
#pragma unroll
    for (int off = 1; off < 64; off <<= 1) {
        s += __shfl_xor(s, off);
        sq += __shfl_xor(sq, off);
    }
    float mu = s * (1.f / 1024.f);
    float var = sq * (1.f / 1024.f) - mu * mu;
    float rstd = rsqrtf(var + 1e-5f);
    const float4* g4 = (const float4*)gamma;
    const float4* b4 = (const float4*)beta;
#pragma unroll
    for (int i = 0; i < 4; i++) {
        float4 g = g4[l + i * 64], b = b4[l + i * 64];
        float y0 = (v[i].x - mu) * rstd * g.x + b.x;
        float y1 = (v[i].y - mu) * rstd * g.y + b.y;
        float y2 = (v[i].z - mu) * rstd * g.z + b.z;
        float y3 = (v[i].w - mu) * rstd * g.w + b.w;
        unsigned int lo = (unsigned int)f2b(y0) | ((unsigned int)f2b(y1) << 16);
        unsigned int hi = (unsigned int)f2b(y2) | ((unsigned int)f2b(y3) << 16);
        uint2 pk;
        pk.x = lo;
        pk.y = hi;
        *(uint2*)(h + row * 1024 + (size_t)(l + i * 64) * 4) = pk;
    }
}

// ---------------------------------------------------------------------------
// Fused QKV-projection + attention (R8 configuration — best measured: 406 us,
// MfmaUtil 41.7%, 4 blocks/CU). One block = 112 rows (4 seqs) x 192 cols
// (one head's q|k|v). 256 threads, 4 waves (1M x 4N), each 112x48 (7x3 frags).
// Decomposition: xcd owns heads {2x,2x+1}; bm fast, head alternating -> B slab
// L2-resident, A panels L3-shared across bm-lockstep XCDs.
// LDS = 38912 B -> 4 blocks/CU.
//   GEMM: sA [0,14336) = 112 rows x 128B (chunk 3 staged by t<128 only);
//         sB [14336,38912) = 192 rows x 128B.
//   Attn (3-phase, aliased):
//     P1: q,k -> qkb swizzled [112][128] u16 @0 (28672B); barrier.
//     P2: QK^T + softmax; sp[w] u16[32][40] @28672 + w*2560 (disjoint); barrier.
//     P3: v (held in regs) -> vt u16[4][64][40] @0 over dead qkb; barrier; PV.
//   NaN containment: wave3 QK^T reads rows 112-115 (sp-region garbage) feed
//   only score rows >=28, which are masked (j>=28 -> -1e30) or discarded (i>=28).
// Closed directions (measured): deep-pipeline (R3), M=224 (R10), dbuf-prefetch
// (R11), fat-wave 7x6 (R12: 168 AGPR + 204 VGPR -> 1 wave/SIMD).
// ---------------------------------------------------------------------------
__global__ __launch_bounds__(256, 4) void fused_qkv_attn(const u16* __restrict__ h,
                                                         const u16* __restrict__ wqkvt,
                                                         u16* __restrict__ ctx) {
    __shared__ __align__(16) char smem[38912];
    char* sA = smem;
    char* sB = smem + 14336;
    int t = threadIdx.x;

    int nwg = gridDim.x;  // 8192
    int cpx = nwg >> 3;
    int wg = ((int)blockIdx.x & 7) * cpx + ((int)blockIdx.x >> 3);
    int x = wg >> 10;                // XCD 0..7
    int i0 = wg & 1023;
    int bm = i0 >> 1;                // 0..511 (fast)
    int head = (x << 1) | (i0 & 1);  // 0..15

    // staging: chunk i covers rows srow + i*32 ; 128B rows, XOR swizzle on source
    int p16 = t * 16;
    int srow = p16 >> 7;  // 0..31
    int scolb = (p16 & 127) ^ ((srow & 7) << 4);
    const char* aB = (const char*)h + ((size_t)bm * 112 + srow) * 2048 + scolb;
    const char* bB = (const char*)wqkvt + ((size_t)head * 192 + srow) * 2048 + scolb;

    int l = t & 63, w = t >> 6, g = l >> 4, lr = l & 15;
    int swz = (lr & 7) << 4;

    f32x4 acc[7][3];
#pragma unroll
    for (int m = 0; m < 7; m++)
#pragma unroll
        for (int n = 0; n < 3; n++) acc[m][n] = {0.f, 0.f, 0.f, 0.f};

#pragma unroll 1
    for (int kt = 0; kt < 16; ++kt) {
        int kb = kt * 128;
#pragma unroll
        for (int i = 0; i < 3; i++) GL2LDS(aB + (size_t)i * 65536 + kb, sA + i * 4096 + p16);
        if (t < 128) GL2LDS(aB + (size_t)3 * 65536 + kb, sA + 3 * 4096 + p16);
#pragma unroll
        for (int i = 0; i < 6; i++) GL2LDS(bB + (size_t)i * 65536 + kb, sB + i * 4096 + p16);
        __syncthreads();
#pragma unroll
        for (int ks = 0; ks < 2; ++ks) {
            bf16x8 af[7], bfv[3];
#pragma unroll
            for (int m = 0; m < 7; m++)
                af[m] = *(const bf16x8*)(sA + (m * 16 + lr) * 128 + ((ks * 64 + g * 16) ^ swz));
#pragma unroll
            for (int n = 0; n < 3; n++)
                bfv[n] = *(const bf16x8*)(sB + (w * 48 + n * 16 + lr) * 128 +
                                          ((ks * 64 + g * 16) ^ swz));
#pragma unroll
            for (int m = 0; m < 7; m++)
#pragma unroll
                for (int n = 0; n < 3; n++) acc[m][n] = MFMA(af[m], bfv[n], acc[m][n]);
        }
        __syncthreads();
    }

    // ---------------- epilogue phase 1: q,k -> swizzled qkb ----------------
    u16* qkb = (u16*)smem;                                    // [112][128] swizzled
    u16(*sp)[40] = (u16(*)[40])(smem + 28672 + w * 2560);     // per-wave P
    u16(*vt)[64][40] = (u16(*)[64][40])smem;                  // phase-3 alias

#pragma unroll
    for (int m = 0; m < 7; m++)
#pragma unroll
        for (int n = 0; n < 3; n++) {
            int col = w * 48 + n * 16 + lr;
            if (col < 128) {
#pragma unroll
                for (int r = 0; r < 4; ++r) {
                    int row = m * 16 + g * 4 + r;
                    qkb[row * 128 + (col ^ ((row & 7) << 3))] = f2b(acc[m][n][r]);
                }
            }
        }
    __syncthreads();

    // ---------------- phase 2: QK^T + softmax ----------------
    int rbase = w * 28;
    f32x4 sc[2][2];
#pragma unroll
    for (int a = 0; a < 2; a++)
#pragma unroll
        for (int c = 0; c < 2; c++) sc[a][c] = {0.f, 0.f, 0.f, 0.f};
#pragma unroll
    for (int c = 0; c < 2; c++) {
        int r0 = rbase + lr, r1 = rbase + 16 + lr;
        int u0 = c * 32 + g * 8;
        bf16x8 a0 = *(const bf16x8*)&qkb[r0 * 128 + (u0 ^ ((r0 & 7) << 3))];
        bf16x8 a1 = *(const bf16x8*)&qkb[r1 * 128 + (u0 ^ ((r1 & 7) << 3))];
        bf16x8 b0 = *(const bf16x8*)&qkb[r0 * 128 + ((64 + u0) ^ ((r0 & 7) << 3))];
        bf16x8 b1 = *(const bf16x8*)&qkb[r1 * 128 + ((64 + u0) ^ ((r1 & 7) << 3))];
        sc[0][0] = MFMA(a0, b0, sc[0][0]);
        sc[0][1] = MFMA(a0, b1, sc[0][1]);
        sc[1][0] = MFMA(a1, b0, sc[1][0]);
        sc[1][1] = MFMA(a1, b1, sc[1][1]);
    }

    float slope = exp2f(-0.5f * (float)(head + 1));
    int j0 = lr, j1 = 16 + lr;
    int j0m = j0 % 14, j0d = j0 / 14;
    int j1m = j1 % 14, j1d = j1 / 14;
#pragma unroll
    for (int it = 0; it < 2; ++it) {
#pragma unroll
        for (int r = 0; r < 4; ++r) {
            int i = it * 16 + g * 4 + r;
            int im = i % 14, id = i / 14;
            float s0 = sc[it][0][r] + slope * (float)(iabs(im - j0m) + iabs(id - j0d));
            float s1 = (j1 < 28)
                           ? sc[it][1][r] + slope * (float)(iabs(im - j1m) + iabs(id - j1d))
                           : -1e30f;
            float mx = fmaxf(s0, s1);
#pragma unroll
            for (int off = 1; off < 16; off <<= 1) mx = fmaxf(mx, __shfl_xor(mx, off));
            float e0 = __expf(s0 - mx), e1 = __expf(s1 - mx);
            float sm = e0 + e1;
#pragma unroll
            for (int off = 1; off < 16; off <<= 1) sm += __shfl_xor(sm, off);
            float inv = 1.f / sm;
            sp[i][lr] = f2b(e0 * inv);
            sp[i][16 + lr] = f2b(e1 * inv);
        }
    }
    __syncthreads();  // all QK^T reads of qkb done -> q/k region reusable

    // ---------------- phase 3: v -> vt, then PV ----------------
    {
        int s2 = t >> 6, d = t & 63;
#pragma unroll
        for (int j = 28; j < 32; ++j) vt[s2][d][j] = 0;
    }
#pragma unroll
    for (int m = 0; m < 7; m++)
#pragma unroll
        for (int n = 0; n < 3; n++) {
            int col = w * 48 + n * 16 + lr;
            if (col >= 128) {
#pragma unroll
                for (int r = 0; r < 4; ++r) {
                    int row = m * 16 + g * 4 + r;
                    int d = col - 128;
                    int s2 = row / 28;
                    int j = row - s2 * 28;
                    vt[s2][d][j] = f2b(acc[m][n][r]);
                }
            }
        }
    __syncthreads();

    // PV (sp same-wave RAW, HW-ordered; vt barrier-covered)
    bf16x8 pa0 = *(const bf16x8*)&sp[lr][g * 8];
    bf16x8 pa1 = *(const bf16x8*)&sp[16 + lr][g * 8];
    f32x4 o[2][4];
#pragma unroll
    for (int a = 0; a < 2; a++)
#pragma unroll
        for (int d = 0; d < 4; d++) o[a][d] = {0.f, 0.f, 0.f, 0.f};
#pragma unroll
    for (int dt = 0; dt < 4; ++dt) {
        bf16x8 bv = *(const bf16x8*)&vt[w][dt * 16 + lr][g * 8];
        o[0][dt] = MFMA(pa0, bv, o[0][dt]);
        o[1][dt] = MFMA(pa1, bv, o[1][dt]);
    }
#pragma unroll
    for (int it = 0; it < 2; ++it)
#pragma unroll
        for (int dt = 0; dt < 4; ++dt)
#pragma unroll
            for (int r = 0; r < 4; ++r) {
                int i = it * 16 + g * 4 + r;
                if (i < 28) {
                    size_t off =
                        ((size_t)(bm * 4 + w) * 28 + i) * 1024 + head * 64 + dt * 16 + lr;
                    ctx[off] = f2b(o[it][dt][r]);
                }
            }
}

// ---------------------------------------------------------------------------
// GEMM (round-1 verbatim): C[M,N] = A[M,1024] bf16 x Bt[N,1024] bf16.
// 128x128 tile, BK=64x2, 256 threads. Used for the output projection.
// ---------------------------------------------------------------------------
template <int OUT_BF16, int RESID>
__global__ __launch_bounds__(256, 2) void gemm_bt(const u16* __restrict__ A,
                                                  const u16* __restrict__ Bt,
                                                  void* __restrict__ Cv,
                                                  const u16* __restrict__ resid,
                                                  int lda, int ldc) {
    __shared__ u16 smem[16384];
    int t = threadIdx.x;

    int nwg = gridDim.x;
    int cpx = nwg >> 3;
    int wg = (blockIdx.x & 7) * cpx + (blockIdx.x >> 3);
    const int sgrp = 448 * 8;
    int sn = wg / sgrp;
    int rem = wg - sn * sgrp;
    int bm = rem >> 3;
    int bn = sn * 8 + (rem & 7);

    const char* Ab = (const char*)A;
    const char* Bb = (const char*)Bt;
    size_t aoffg[4], boffg[4];
#pragma unroll
    for (int i = 0; i < 4; i++) {
        int p = t * 16 + i * 4096;
        int row = p >> 7;
        int colb = (p & 127) ^ ((row & 7) << 4);
        aoffg[i] = (size_t)(bm * 128 + row) * (size_t)lda * 2 + colb;
        boffg[i] = (size_t)(bn * 128 + row) * 2048 + colb;
    }
    char* sA = (char*)smem;
    char* sB = sA + 16384;

    int l = t & 63, w = t >> 6;
    int wm = w >> 1, wn = w & 1, g = l >> 4, lr = l & 15;
    int swz = (lr & 7) << 4;

    f32x4 acc[4][4];
#pragma unroll
    for (int m = 0; m < 4; m++)
#pragma unroll
        for (int n = 0; n < 4; n++) acc[m][n] = {0.f, 0.f, 0.f, 0.f};

    for (int kt = 0; kt < 16; ++kt) {
        int kb = kt * 128;
#pragma unroll
        for (int i = 0; i < 4; i++) GL2LDS(Ab + aoffg[i] + kb, sA + i * 4096 + t * 16);
#pragma unroll
        for (int i = 0; i < 4; i++) GL2LDS(Bb + boffg[i] + kb, sB + i * 4096 + t * 16);
        __syncthreads();
#pragma unroll
        for (int ks = 0; ks < 2; ++ks) {
            bf16x8 af[4], bfv[4];
#pragma unroll
            for (int m = 0; m < 4; m++)
                af[m] = *(const bf16x8*)(sA + (wm * 64 + m * 16 + lr) * 128 +
                                         ((ks * 64 + g * 16) ^ swz));
#pragma unroll
            for (int n = 0; n < 4; n++)
                bfv[n] = *(const bf16x8*)(sB + (wn * 64 + n * 16 + lr) * 128 +
                                          ((ks * 64 + g * 16) ^ swz));
#pragma unroll
            for (int m = 0; m < 4; m++)
#pragma unroll
                for (int n = 0; n < 4; n++)
                    acc[m][n] = MFMA(af[m], bfv[n], acc[m][n]);
        }
        __syncthreads();
    }

    size_t row0 = (size_t)bm * 128 + wm * 64;
    int col0 = bn * 128 + wn * 64;
    if (OUT_BF16) {
        u16* C = (u16*)Cv;
#pragma unroll
        for (int m = 0; m < 4; m++)
#pragma unroll
            for (int n = 0; n < 4; n++)
#pragma unroll
                for (int r = 0; r < 4; r++) {
                    size_t rr = row0 + m * 16 + g * 4 + r;
                    int cc = col0 + n * 16 + lr;
                    C[rr * (size_t)ldc + cc] = f2b(acc[m][n][r]);
                }
    } else {
        float* C = (float*)Cv;
#pragma unroll
        for (int m = 0; m < 4; m++)
#pragma unroll
            for (int n = 0; n < 4; n++)
#pragma unroll
                for (int r = 0; r < 4; r++) {
                    size_t rr = row0 + m * 16 + g * 4 + r;
                    int cc = col0 + n * 16 + lr;
                    float o = acc[m][n][r];
                    if (RESID) o += b2f(resid[rr * 1024 + cc]);
                    C[rr * (size_t)ldc + cc] = o;
                }
    }
}

// ---------------------------------------------------------------------------
extern "C" void kernel_launch(void* const* d_in, const int* in_sizes, int n_in,
                              void* d_out, int out_size, void* d_ws, size_t ws_size,
                              hipStream_t stream) {
    (void)in_sizes; (void)n_in; (void)out_size; (void)ws_size;
    const float* hidden = (const float*)d_in[0];
    const float* wq = (const float*)d_in[1];
    const float* wk = (const float*)d_in[2];
    const float* wv = (const float*)d_in[3];
    const float* wo = (const float*)d_in[4];
    const float* gamma = (const float*)d_in[5];
    const float* beta = (const float*)d_in[6];
    float* out = (float*)d_out;

    char* ws = (char*)d_ws;
    u16* h = (u16*)ws;                                  // 117,440,512 B
    u16* ctx = (u16*)(ws + 117440512);                  // 117,440,512 B
    u16* wqkvt = (u16*)(ws + 234881024);                //   6,291,456 B
    u16* wot = (u16*)(ws + 234881024 + 6291456);        //   2,097,152 B

    wconv_kernel<<<dim3(32, 32, 4), 256, 0, stream>>>(wq, wk, wv, wo, wqkvt, wot);
    ln_kernel<<<14336, 256, 0, stream>>>(hidden, gamma, beta, h);
    fused_qkv_attn<<<8192, 256, 0, stream>>>(h, wqkvt, ctx);
    // ctx is dense [57344][1024] -> lda = 1024
    gemm_bt<0, 1><<<448 * 8, 256, 0, stream>>>(ctx, wot, out, h, 1024, 1024);
}